// Round 3
// baseline (368.019 us; speedup 1.0000x reference)
//
#include <hip/hip_runtime.h>

// LSTM, barrier-free per-wave MFMA formulation. Round 10 (resubmit after
// infra failure): 4 batches/wave. B=4096, T=512, I=10, H=32, O=1.
//
// R9 counters: MfmaUtil 42%, VALUBusy 52%, window ~1330 cyc/SIMD with
// VALU+MFMA summing to ~the whole window -> the 2 resident waves phase-lock
// (no cross-wave MFMA/VALU overlap), and each MFMA output is only 25% used
// (2 batches dup-8 across 16 A-rows, C reg 0 only).
//
// R10: 4 batches per wave, dup-4 (A row m = batch m>>2). C row = 4Q+reg,
// so reg 0 of quad Q = batch Q -> same 16 MFMAs/step now serve 4 batches:
// MFMA pipe demand per SIMD per timestep halves (620 -> 310 cyc). Grid
// drops to 1024 waves = 1 wave/SIMD: no phase-lock partner; within-wave
// ILP (8 independent 2-deep MFMA chains, 8-gate activation ILP across the
// lane's 2 cells) covers latency.
//
// Activation mapping: lane (Q=lane>>4, L=lane&15) handles batch Q, hids
// {L, L+16}: cell0 gates = v[0],v[2],v[4],v[6] (tile hhalf 0), cell1 =
// v[1],v[3],v[5],v[7]. All in-lane, no cross-lane moves, no qh selects.
//
// K-packing unchanged from R9 (64/64 slots per tile):
//   MFMA 1 (per tile): A = h_hi (k0..31),               B = W_hh
//   MFMA 2 (per tile): A = {x_hat k0..9 | h_lo k10..31}, B = {W_ih | W_hh}
// fp16 2-term h split; h_lo correction dropped on channels 0..9 only
// (verified R9, absmax 2e-3). Biases folded into the sigmoid fma.
//
// h round-trips through a private per-wave LDS buffer (wave-ordered DS =>
// NO barriers ever). hbuf [2][2][4][32] fp16 = 1 KiB.
//
// Grid: 1024 blocks x 64 threads (1 wave/block), 4 batches/wave,
// launch_bounds(64,1) -> full VGPR budget for one wave/SIMD.

#define T_SZ 512
#define I_SZ 10
#define H_SZ 32

typedef _Float16 half8  __attribute__((ext_vector_type(8)));
typedef __fp16   fp16x2 __attribute__((ext_vector_type(2)));
typedef float    f32x4  __attribute__((ext_vector_type(4)));
typedef int      i32x4  __attribute__((ext_vector_type(4)));

union FH { i32x4 i; half8 h; };
static __device__ __forceinline__ half8 fragv(i32x4 v) { FH u; u.i = v; return u.h; }
static __device__ __forceinline__ half8 frag4(int a, int b, int c, int d) {
    FH u; u.i = (i32x4){a, b, c, d}; return u.h;
}

// pack 2 fp32 -> 2 fp16 in one dword (v_cvt_pkrtz_f16_f32): low = lo, high = hi
static __device__ __forceinline__ int pk16(float lo, float hi) {
    union { fp16x2 h; int i; } u;
    u.h = __builtin_amdgcn_cvt_pkrtz(lo, hi);
    return u.i;
}

#define MFMAH(A, B, C) __builtin_amdgcn_mfma_f32_16x16x32_f16((A), (B), (C), 0, 0, 0)

__global__ __launch_bounds__(64, 1)
void lstm_wave(const float* __restrict__ x, const float* __restrict__ W_ih,
               const float* __restrict__ W_hh, const float* __restrict__ b_ih,
               const float* __restrict__ b_hh, const float* __restrict__ W_dense,
               const float* __restrict__ b_dense, float* __restrict__ out)
{
    const int lane  = threadIdx.x;        // 0..63 (block = one wave)
    const int L     = lane & 15;          // A m-row / C col
    const int Q     = lane >> 4;          // k-quad / C row-quad (= act batch)
    const int bbase = blockIdx.x * 4;     // 1024 blocks x 4 batches

    const int bA = L >> 2;                // A-side batch (4 dup rows per batch)
    const int h0 = L, h1 = L + 16;        // this lane's two hidden channels

    // ---- B-fragments for all 8 tiles (one-time) ----
    // tile tau = 2*gate + hhalf: W row = 32*gate + 16*hhalf + L
    // bhh: k0..31 = W_hh cols (pairs with h_hi A-frag)
    // bm : k0..9 = W_ih, k10..31 = W_hh cols 10..31 (pairs with merged frag)
    int bhh[8][4];
    int bm[8][4];
    #pragma unroll
    for (int tau = 0; tau < 8; ++tau) {
        const int wr = 32 * (tau >> 1) + 16 * (tau & 1) + L;
        const float* ph = W_hh + wr * H_SZ + 8 * Q;
        #pragma unroll
        for (int d = 0; d < 4; ++d) {
            float2 v = *(const float2*)(ph + 2 * d);
            bhh[tau][d] = pk16(v.x, v.y);
        }
        if (Q == 0) {
            const float* pi = W_ih + wr * I_SZ;       // k0..7 = W_ih cols 0..7
            #pragma unroll
            for (int d = 0; d < 4; ++d) {
                float2 v = *(const float2*)(pi + 2 * d);
                bm[tau][d] = pk16(v.x, v.y);
            }
        } else if (Q == 1) {
            // k8,9 = W_ih cols 8,9; k10..15 = W_hh cols 10..15
            float2 v = *(const float2*)(W_ih + wr * I_SZ + 8);
            bm[tau][0] = pk16(v.x, v.y);
            #pragma unroll
            for (int d = 1; d < 4; ++d) {
                float2 w = *(const float2*)(W_hh + wr * H_SZ + 8 + 2 * d);
                bm[tau][d] = pk16(w.x, w.y);
            }
        } else {
            bm[tau][0] = bhh[tau][0]; bm[tau][1] = bhh[tau][1];
            bm[tau][2] = bhh[tau][2]; bm[tau][3] = bhh[tau][3];
        }
    }

    // ---- biases folded into sigmoid fma, for BOTH hidden channels ----
    const float nL = -1.4426950f;     // -log2(e)       (sigmoid)
    const float m2 = -2.8853901f;     // -2*log2(e)     (tanh via 2*sig(2x)-1)
    const float mbi0 = nL * (b_ih[h0]      + b_hh[h0]);
    const float mbf0 = nL * (b_ih[32 + h0] + b_hh[32 + h0]);
    const float mbg0 = m2 * (b_ih[64 + h0] + b_hh[64 + h0]);
    const float mbo0 = nL * (b_ih[96 + h0] + b_hh[96 + h0]);
    const float mbi1 = nL * (b_ih[h1]      + b_hh[h1]);
    const float mbf1 = nL * (b_ih[32 + h1] + b_hh[32 + h1]);
    const float mbg1 = m2 * (b_ih[64 + h1] + b_hh[64 + h1]);
    const float mbo1 = nL * (b_ih[96 + h1] + b_hh[96 + h1]);

    // ---- per-wave LDS h buffer: [buf][plane hi/lo][batch 0..3][hid] fp16 ----
    __shared__ __attribute__((aligned(16))) _Float16 hbuf[2][2][4][H_SZ];  // 1 KiB
    {
        int* zz = (int*)&hbuf[0][0][0][0];
        zz[lane] = 0; zz[lane + 64] = 0; zz[lane + 128] = 0; zz[lane + 192] = 0;
    }
    // wave-ordered DS: zeros visible to this wave's later reads, no barrier.

    // ---- x stream: 2-deep prefetch (each lane loads its A-side batch row) ----
    const float* xrow = x + (size_t)(bbase + bA) * (T_SZ * I_SZ);
    float2 xa0 = *(const float2*)(xrow + 0), xa1 = *(const float2*)(xrow + 2),
           xa2 = *(const float2*)(xrow + 4), xa3 = *(const float2*)(xrow + 6),
           xa4 = *(const float2*)(xrow + 8);
    float2 xb0 = *(const float2*)(xrow + I_SZ + 0), xb1 = *(const float2*)(xrow + I_SZ + 2),
           xb2 = *(const float2*)(xrow + I_SZ + 4), xb3 = *(const float2*)(xrow + I_SZ + 6),
           xb4 = *(const float2*)(xrow + I_SZ + 8);

    const f32x4 zerov = {0.f, 0.f, 0.f, 0.f};
    float cst0 = 0.0f, cst1 = 0.0f;
    float h0last = 0.0f, h1last = 0.0f;
    const bool q0 = (Q == 0), q1 = (Q == 1);

    for (int t = 0; t < T_SZ; t += 2) {
        #pragma unroll
        for (int u = 0; u < 2; ++u) {
            const int rb = u, wb = u ^ 1;

            // h fragments from private LDS (A-frag order, broadcast reads)
            const _Float16* hp = &hbuf[rb][0][bA][8 * Q];
            const _Float16* lp = &hbuf[rb][1][bA][8 * Q];
            i32x4 hhi_ = *(const i32x4*)hp;
            i32x4 lo_  = *(const i32x4*)lp;   // h_lo channels 8Q..8Q+7

            // x_hat packs (this lane's batch row)
            float2 y0 = u ? xb0 : xa0, y1 = u ? xb1 : xa1, y2 = u ? xb2 : xa2,
                   y3 = u ? xb3 : xa3, y4 = u ? xb4 : xa4;
            int p0 = pk16(y0.x, y0.y), p1 = pk16(y1.x, y1.y), p2 = pk16(y2.x, y2.y),
                p3 = pk16(y3.x, y3.y), p4 = pk16(y4.x, y4.y);

            // merged A-frag: k0..9 = x_hat, k10..31 = h_lo channels 10..31
            half8 mf = fragv((i32x4){ q0 ? p0 : (q1 ? p4 : lo_[0]),
                                      q0 ? p1 : lo_[1],
                                      q0 ? p2 : lo_[2],
                                      q0 ? p3 : lo_[3] });

            // refill consumed set from t+2+u (distance-2 prefetch)
            if (t + 2 + u < T_SZ) {
                const float* xr = xrow + (t + 2 + u) * I_SZ;
                if (u == 0) {
                    xa0 = *(const float2*)(xr + 0); xa1 = *(const float2*)(xr + 2);
                    xa2 = *(const float2*)(xr + 4); xa3 = *(const float2*)(xr + 6);
                    xa4 = *(const float2*)(xr + 8);
                } else {
                    xb0 = *(const float2*)(xr + 0); xb1 = *(const float2*)(xr + 2);
                    xb2 = *(const float2*)(xr + 4); xb3 = *(const float2*)(xr + 6);
                    xb4 = *(const float2*)(xr + 8);
                }
            }

            // 8 independent 2-deep MFMA chains; keep C reg 0 of each
            half8 hhi = fragv(hhi_);
            float v[8];
            #pragma unroll
            for (int tau = 0; tau < 8; ++tau) {
                f32x4 acc = MFMAH(mf, frag4(bm[tau][0], bm[tau][1], bm[tau][2], bm[tau][3]), zerov);
                acc = MFMAH(hhi, frag4(bhh[tau][0], bhh[tau][1], bhh[tau][2], bhh[tau][3]), acc);
                v[tau] = acc[0];
            }

            // cell 0: (batch Q, hid L) -- gates from even tiles
            float ig0 = __builtin_amdgcn_rcpf(1.0f + __builtin_amdgcn_exp2f(fmaf(nL, v[0], mbi0)));
            float fg0 = __builtin_amdgcn_rcpf(1.0f + __builtin_amdgcn_exp2f(fmaf(nL, v[2], mbf0)));
            float gr0 = __builtin_amdgcn_rcpf(1.0f + __builtin_amdgcn_exp2f(fmaf(m2, v[4], mbg0)));
            float gg0 = fmaf(2.0f, gr0, -1.0f);
            float og0 = __builtin_amdgcn_rcpf(1.0f + __builtin_amdgcn_exp2f(fmaf(nL, v[6], mbo0)));
            cst0 = fmaf(fg0, cst0, ig0 * gg0);
            float tr0 = __builtin_amdgcn_rcpf(1.0f + __builtin_amdgcn_exp2f(m2 * cst0));
            float th0 = fmaf(2.0f, tr0, -1.0f);
            float hv0 = og0 * th0;
            h0last = hv0;

            // cell 1: (batch Q, hid L+16) -- gates from odd tiles
            float ig1 = __builtin_amdgcn_rcpf(1.0f + __builtin_amdgcn_exp2f(fmaf(nL, v[1], mbi1)));
            float fg1 = __builtin_amdgcn_rcpf(1.0f + __builtin_amdgcn_exp2f(fmaf(nL, v[3], mbf1)));
            float gr1 = __builtin_amdgcn_rcpf(1.0f + __builtin_amdgcn_exp2f(fmaf(m2, v[5], mbg1)));
            float gg1 = fmaf(2.0f, gr1, -1.0f);
            float og1 = __builtin_amdgcn_rcpf(1.0f + __builtin_amdgcn_exp2f(fmaf(nL, v[7], mbo1)));
            cst1 = fmaf(fg1, cst1, ig1 * gg1);
            float tr1 = __builtin_amdgcn_rcpf(1.0f + __builtin_amdgcn_exp2f(m2 * cst1));
            float th1 = fmaf(2.0f, tr1, -1.0f);
            float hv1 = og1 * th1;
            h1last = hv1;

            // h write-back, fp16 2-term split, [plane][batch][hid] layout
            _Float16 a0h = (_Float16)hv0;
            _Float16 a0l = (_Float16)(hv0 - (float)a0h);
            _Float16 a1h = (_Float16)hv1;
            _Float16 a1l = (_Float16)(hv1 - (float)a1h);
            hbuf[wb][0][Q][h0] = a0h;
            hbuf[wb][0][Q][h1] = a1h;
            hbuf[wb][1][Q][h0] = a0l;
            hbuf[wb][1][Q][h1] = a1l;
            // wave-ordered DS: next iteration's reads see these writes.
        }
    }

    // ---- dense head: out[b] = h . W_dense + b_dense ----
    // lane (Q,L) holds hids {L, L+16} of batch Q; reduce over the 16-lane quad
    float v = h0last * W_dense[h0] + h1last * W_dense[h1];
    #pragma unroll
    for (int m = 8; m >= 1; m >>= 1)
        v += __shfl_xor(v, m);            // reduce within each 16-lane quad
    if (L == 0) out[bbase + Q] = v + b_dense[0];
}

extern "C" void kernel_launch(void* const* d_in, const int* in_sizes, int n_in,
                              void* d_out, int out_size, void* d_ws, size_t ws_size,
                              hipStream_t stream) {
    const float* x       = (const float*)d_in[0];
    const float* W_ih    = (const float*)d_in[1];
    const float* W_hh    = (const float*)d_in[2];
    const float* b_ih    = (const float*)d_in[3];
    const float* b_hh    = (const float*)d_in[4];
    const float* W_dense = (const float*)d_in[5];
    const float* b_dense = (const float*)d_in[6];
    float* out = (float*)d_out;

    // 1024 blocks x 64 threads = 1024 independent waves (1/SIMD), 4 batches each
    lstm_wave<<<dim3(1024), dim3(64), 0, stream>>>(
        x, W_ih, W_hh, b_ih, b_hh, W_dense, b_dense, out);
}